// Round 4
// baseline (353.575 us; speedup 1.0000x reference)
//
#include <hip/hip_runtime.h>

// Problem constants (match reference)
constexpr int B = 1024, N = 100, C = 256, K = 3;
constexpr int ROWS = B * N;              // 102400
constexpr int LANES_PER_ROW = 16;        // 16 lanes cooperate on one row
constexpr int CH_PER_LANE = 16;          // C / LANES_PER_ROW -> 4 x float4 per lane
constexpr int ROWS_PER_WAVE = 4;         // 64 / 16
constexpr int WAVES_PER_BLOCK = 4;       // 256 threads
constexpr int ROWS_PER_BLOCK = ROWS_PER_WAVE * WAVES_PER_BLOCK;  // 16
constexpr int BLOCKS = ROWS / ROWS_PER_BLOCK;                    // 6400, exact
constexpr float LN_EPS = 1e-5f;

// Native clang vector type (accepted by __builtin_nontemporal_store)
typedef float nfloat4 __attribute__((ext_vector_type(4)));

__global__ __launch_bounds__(256) void dydwconv_ln_kernel(
    const float* __restrict__ query,   // [B,N,C]
    const float* __restrict__ value,   // [B,N,C]
    const float* __restrict__ Ww,      // [K,C]
    const float* __restrict__ bw,      // [K]
    const float* __restrict__ gamma,   // [C]
    const float* __restrict__ beta,    // [C]
    float* __restrict__ out)           // [B,N,C]
{
    __shared__ float sW[K * C];        // 3 KB
    __shared__ float sGamma[C];
    __shared__ float sBeta[C];

    const int t = threadIdx.x;
    sW[t]         = Ww[t];
    sW[t + C]     = Ww[t + C];
    sW[t + 2 * C] = Ww[t + 2 * C];
    sGamma[t] = gamma[t];
    sBeta[t]  = beta[t];
    __syncthreads();

    const int wave = t >> 6;
    const int lane = t & 63;
    const int l    = lane & (LANES_PER_ROW - 1);   // position within row [0,16)
    const int sub  = lane >> 4;                    // row slot within wave [0,4)
    const int row  = (blockIdx.x * WAVES_PER_BLOCK + wave) * ROWS_PER_WAVE + sub;
    const int c0   = l * CH_PER_LANE;              // first channel owned by this lane

    const size_t base = (size_t)row * C + c0;

    // 8 vectorized global loads per wave (16 B/lane each), covering 4 rows
    nfloat4 q4[4], v4[4];
    #pragma unroll
    for (int j = 0; j < 4; ++j) {
        q4[j] = *(const nfloat4*)(query + base + 4 * j);
        v4[j] = *(const nfloat4*)(value + base + 4 * j);
    }

    // Dynamic-kernel partial dots over this lane's 16 channels
    float p0 = 0.f, p1 = 0.f, p2 = 0.f;
    #pragma unroll
    for (int j = 0; j < 4; ++j) {
        const nfloat4 qq = q4[j];
        const nfloat4 a = *(const nfloat4*)(sW + c0 + 4 * j);
        const nfloat4 b = *(const nfloat4*)(sW + C + c0 + 4 * j);
        const nfloat4 c = *(const nfloat4*)(sW + 2 * C + c0 + 4 * j);
        p0 += qq.x * a.x + qq.y * a.y + qq.z * a.z + qq.w * a.w;
        p1 += qq.x * b.x + qq.y * b.y + qq.z * b.z + qq.w * b.w;
        p2 += qq.x * c.x + qq.y * c.y + qq.z * c.z + qq.w * c.w;
    }
    // Reduce across the 16 lanes of this row: 4 butterfly steps
    // (one instruction reduces all 4 rows of the wave simultaneously)
    #pragma unroll
    for (int off = 8; off > 0; off >>= 1) {
        p0 += __shfl_xor(p0, off);
        p1 += __shfl_xor(p1, off);
        p2 += __shfl_xor(p2, off);
    }
    const float w0 = p0 + bw[0];
    const float w1 = p1 + bw[1];
    const float w2 = p2 + bw[2];

    // Conv halo across lane boundary (zeroed at row edges; masking also
    // prevents leakage across the 16-lane row groups)
    float vl = __shfl_up(v4[3].w, 1);      // channel c0-1
    float vr = __shfl_down(v4[0].x, 1);    // channel c0+16
    if (l == 0)                  vl = 0.0f;
    if (l == LANES_PER_ROW - 1)  vr = 0.0f;

    // K=3 cross-correlation + LN partial stats over 16 channels
    float o[CH_PER_LANE];
    float s = 0.f, ss = 0.f;
    #pragma unroll
    for (int j = 0; j < CH_PER_LANE; ++j) {
        const float left  = (j == 0)  ? vl : v4[(j - 1) >> 2][(j - 1) & 3];
        const float mid   = v4[j >> 2][j & 3];
        const float right = (j == 15) ? vr : v4[(j + 1) >> 2][(j + 1) & 3];
        o[j] = left * w0 + mid * w1 + right * w2;
        s  += o[j];
        ss += o[j] * o[j];
    }
    // LN reduction: 4 butterfly steps over the 16-lane group
    #pragma unroll
    for (int off = 8; off > 0; off >>= 1) {
        s  += __shfl_xor(s,  off);
        ss += __shfl_xor(ss, off);
    }
    const float mu  = s * (1.0f / C);
    const float var = ss * (1.0f / C) - mu * mu;
    const float inv = rsqrtf(var + LN_EPS);

    // Normalize + affine + NT store (4 x 16 B per lane)
    #pragma unroll
    for (int j = 0; j < 4; ++j) {
        const nfloat4 g  = *(const nfloat4*)(sGamma + c0 + 4 * j);
        const nfloat4 be = *(const nfloat4*)(sBeta  + c0 + 4 * j);
        nfloat4 res;
        res.x = (o[4 * j + 0] - mu) * inv * g.x + be.x;
        res.y = (o[4 * j + 1] - mu) * inv * g.y + be.y;
        res.z = (o[4 * j + 2] - mu) * inv * g.z + be.z;
        res.w = (o[4 * j + 3] - mu) * inv * g.w + be.w;
        __builtin_nontemporal_store(res, (nfloat4*)(out + base + 4 * j));
    }
}

extern "C" void kernel_launch(void* const* d_in, const int* in_sizes, int n_in,
                              void* d_out, int out_size, void* d_ws, size_t ws_size,
                              hipStream_t stream) {
    const float* query = (const float*)d_in[0];
    const float* value = (const float*)d_in[1];
    const float* Ww    = (const float*)d_in[2];
    const float* bw    = (const float*)d_in[3];
    const float* gamma = (const float*)d_in[4];
    const float* beta  = (const float*)d_in[5];
    float* out = (float*)d_out;

    dydwconv_ln_kernel<<<BLOCKS, 256, 0, stream>>>(query, value, Ww, bw, gamma, beta, out);
}